// Round 1
// baseline (62674.182 us; speedup 1.0000x reference)
//
#include <hip/hip_runtime.h>

// Seq2Seq VAE fused persistent kernel for MI355X (gfx950).
// 8 independent groups (one per XCD-hint) of 32 WGs; each group owns 128 batch
// rows and runs encoder(1024) -> mu/logvar/z -> decoder(1024) with per-group
// barriers. Weights live persistently in LDS (146KB/CU), bf16 MFMA 16x16x32.

#define NWG  256
#define NTHR 256

typedef __attribute__((ext_vector_type(8))) short short8;
typedef __attribute__((ext_vector_type(4))) float f32x4;

constexpr int Bt = 1024;   // batch
constexpr int Tt = 1024;   // seq len (enc and dec)
constexpr int In = 64;     // input size
constexpr int Hn = 512;    // hidden
constexpr int Ln = 64;     // latent
constexpr int KE = In + Hn;      // 576 (encoder GEMM K)
constexpr int BSE = KE + 8;      // padded LDS row stride (shorts)
constexpr int KD = Hn;           // 512 (decoder GEMM K)
constexpr int BSD = KD + 8;      // 520
constexpr int LDS_BYTES = 128 * BSE * 2;   // 149504 B

__device__ __forceinline__ float bf2f(unsigned short s){
  unsigned u = ((unsigned)s) << 16; float f; __builtin_memcpy(&f, &u, 4); return f;
}
__device__ __forceinline__ unsigned short f2bf(float f){
  unsigned u; __builtin_memcpy(&u, &f, 4);
  u += 0x7FFFu + ((u >> 16) & 1u);            // RNE (finite inputs)
  return (unsigned short)(u >> 16);
}
__device__ __forceinline__ float sigm(float x){ return 1.0f / (1.0f + __expf(-x)); }
__device__ __forceinline__ float tanh_(float x){ float e = __expf(2.0f * x); return 1.0f - 2.0f / (e + 1.0f); }

// 32-WG group barrier. Plain stores + agent release fence before arrive,
// agent acquire fence after -> cross-XCD correct per gfx94x/95x memory model.
__device__ __forceinline__ void group_sync(unsigned* cnt, unsigned target){
  __builtin_amdgcn_fence(__ATOMIC_RELEASE, "agent");
  __syncthreads();
  if (threadIdx.x == 0){
    __hip_atomic_fetch_add(cnt, 1u, __ATOMIC_RELAXED, __HIP_MEMORY_SCOPE_AGENT);
    while (__hip_atomic_load(cnt, __ATOMIC_RELAXED, __HIP_MEMORY_SCOPE_AGENT) < target)
      __builtin_amdgcn_s_sleep(4);
  }
  __syncthreads();
  __builtin_amdgcn_fence(__ATOMIC_ACQUIRE, "agent");
}

extern "C" __global__ void __launch_bounds__(NTHR, 1)
vae_fused(const float* __restrict__ src, const float* __restrict__ eps,
          const float* __restrict__ Wih_e, const float* __restrict__ Whh_e, const float* __restrict__ b_e,
          const float* __restrict__ Wmu, const float* __restrict__ bmu,
          const float* __restrict__ Wlv, const float* __restrict__ blv,
          const float* __restrict__ Wzh, const float* __restrict__ bzh,
          const float* __restrict__ Wzc, const float* __restrict__ bzc,
          const float* __restrict__ Wih_d, const float* __restrict__ Whh_d, const float* __restrict__ b_d,
          const float* __restrict__ Wout, const float* __restrict__ bout,
          float* __restrict__ out,
          unsigned* cnt_all, unsigned short* hbuf0, unsigned short* hbuf1,
          float* zbuf, float* obuf)
{
  const int tid  = threadIdx.x;
  const int wg   = blockIdx.x;
  const int lane = tid & 63;
  const int wave = tid >> 6;
  const int wm   = wave >> 1, wn = wave & 1;  // 2x2 wave tiling of 64x128
  const int g    = wg & 7;                    // group (XCD hint)
  const int idxg = wg >> 3;                   // 0..31 within group
  const int nt   = idxg & 15;                 // N tile (128 gate-cols)
  const int mt   = g * 2 + (idxg >> 4);       // M tile (64 rows), group-local rows
  unsigned* cnt  = cnt_all + g * 32;          // 128B-spaced counters
  unsigned bars  = 0;

  extern __shared__ short bpanel[];           // [128][BSE or BSD]

  const int l15   = lane & 15;
  const int l4    = lane >> 4;
  const int kq    = l4 * 8;                   // K sub-offset of this lane's fragment
  const int jcol  = nt * 32 + wn * 16 + l15;  // this lane's hidden index j
  const int arow0 = mt * 64 + wm * 32 + l15;  // A-fragment row base
  const int brow0 = mt * 64 + wm * 32 + l4 * 4; // C/D row base

  // ---------------- prep: zero h0 (group rows), build encoder B panel ----------------
  {
    const int lt = idxg * NTHR + tid;         // 0..8191 -> exactly 128*512 ushort /16B
    uint4* p = (uint4*)(hbuf0 + (size_t)(g * 128) * Hn);
    p[lt] = make_uint4(0u, 0u, 0u, 0u);
  }
  for (int idx = tid; idx < 128 * KE; idx += NTHR){
    int q = idx / KE;
    int k = idx - q * KE;
    int gate = (q >> 4) & 3, jl = q & 15, wnn = (q >> 6) & 1;
    int j = nt * 32 + wnn * 16 + jl;
    int r = gate * Hn + j;
    float v = (k < In) ? Wih_e[r * In + k] : Whh_e[(size_t)r * Hn + (k - In)];
    bpanel[q * BSE + k] = (short)f2bf(v);
  }
  float biasr[4], wihr[4];
  #pragma unroll
  for (int ni = 0; ni < 4; ++ni) biasr[ni] = b_e[ni * Hn + jcol];
  bars += 32; group_sync(cnt, bars);

  float c[2][4] = {{0.f,0.f,0.f,0.f},{0.f,0.f,0.f,0.f}};
  const f32x4 fz = {0.f, 0.f, 0.f, 0.f};

  // ---------------- encoder: 1024 steps ----------------
  for (int t = 0; t < Tt; ++t){
    const unsigned short* hs = (t & 1) ? hbuf1 : hbuf0;
    unsigned short*       hd = (t & 1) ? hbuf0 : hbuf1;
    f32x4 acc[2][4];
    #pragma unroll
    for (int mi = 0; mi < 2; ++mi)
      #pragma unroll
      for (int ni = 0; ni < 4; ++ni) acc[mi][ni] = fz;

    const short* bbase = bpanel + (wn * 64 + l15) * BSE + kq;

    // K = 0..64 : x_t from src (fp32 -> bf16 in-register)
    #pragma unroll
    for (int k0 = 0; k0 < In; k0 += 32){
      short8 a[2];
      #pragma unroll
      for (int mi = 0; mi < 2; ++mi){
        const float* sp = src + ((size_t)(arow0 + mi * 16) * Tt + t) * In + k0 + kq;
        f32x4 f0 = *(const f32x4*)sp;
        f32x4 f1 = *(const f32x4*)(sp + 4);
        short8 av;
        #pragma unroll
        for (int e = 0; e < 4; ++e){ av[e] = (short)f2bf(f0[e]); av[4 + e] = (short)f2bf(f1[e]); }
        a[mi] = av;
      }
      #pragma unroll
      for (int ni = 0; ni < 4; ++ni){
        short8 bv = *(const short8*)(bbase + ni * 16 * BSE + k0);
        #pragma unroll
        for (int mi = 0; mi < 2; ++mi)
          acc[mi][ni] = __builtin_amdgcn_mfma_f32_16x16x32_bf16(a[mi], bv, acc[mi][ni], 0, 0, 0);
      }
    }
    // K = 64..576 : h_t from global (bf16, L2-resident)
    const unsigned short* ap = hs + (size_t)arow0 * Hn + kq;
    #pragma unroll 4
    for (int k0 = In; k0 < KE; k0 += 32){
      short8 a[2];
      #pragma unroll
      for (int mi = 0; mi < 2; ++mi)
        a[mi] = *(const short8*)(ap + mi * 16 * Hn + (k0 - In));
      #pragma unroll
      for (int ni = 0; ni < 4; ++ni){
        short8 bv = *(const short8*)(bbase + ni * 16 * BSE + k0);
        #pragma unroll
        for (int mi = 0; mi < 2; ++mi)
          acc[mi][ni] = __builtin_amdgcn_mfma_f32_16x16x32_bf16(a[mi], bv, acc[mi][ni], 0, 0, 0);
      }
    }
    // gates -> (h, c); c stays in registers, h -> other buffer (bf16)
    #pragma unroll
    for (int mi = 0; mi < 2; ++mi){
      #pragma unroll
      for (int r = 0; r < 4; ++r){
        float gi = acc[mi][0][r] + biasr[0];
        float gf = acc[mi][1][r] + biasr[1];
        float gg = acc[mi][2][r] + biasr[2];
        float go = acc[mi][3][r] + biasr[3];
        float cn = sigm(gf) * c[mi][r] + sigm(gi) * tanh_(gg);
        c[mi][r] = cn;
        float hn = sigm(go) * tanh_(cn);
        hd[(size_t)(brow0 + mi * 16 + r) * Hn + jcol] = f2bf(hn);
      }
    }
    bars += 32; group_sync(cnt, bars);
  }
  // h_n is now in hbuf0 (1024 steps -> last write had t&1==1 -> hd==hbuf0)

  // ---------------- mu / logvar / z ----------------
  {
    const int lt = idxg * NTHR + tid;   // 8192 threads/group == 128 rows * 64 latents
    const int b  = g * 128 + (lt >> 6);
    const int l  = lt & 63;
    const unsigned short* hp = hbuf0 + (size_t)b * Hn;
    const float* wmrow = Wmu + l * Hn;
    const float* wlrow = Wlv + l * Hn;
    float smu = 0.f, slv = 0.f;
    for (int jj = 0; jj < Hn; jj += 8){
      short8 hv = *(const short8*)(hp + jj);
      #pragma unroll
      for (int e = 0; e < 8; ++e){
        float hf = bf2f((unsigned short)hv[e]);
        smu = __builtin_fmaf(hf, wmrow[jj + e], smu);
        slv = __builtin_fmaf(hf, wlrow[jj + e], slv);
      }
    }
    smu += bmu[l]; slv += blv[l];
    out[(size_t)Bt * Tt + (size_t)b * Ln + l] = smu;
    out[(size_t)Bt * Tt + (size_t)Bt * Ln + (size_t)b * Ln + l] = slv;
    zbuf[(size_t)b * Ln + l] = smu + eps[(size_t)b * Ln + l] * __expf(0.5f * slv);
  }
  bars += 32; group_sync(cnt, bars);

  // ---------------- decoder init: B panel (K=512), h_d/c_d, out buffers ----------------
  for (int idx = tid; idx < 128 * KD; idx += NTHR){
    int q = idx >> 9, k = idx & 511;
    int gate = (q >> 4) & 3, jl = q & 15, wnn = (q >> 6) & 1;
    int j = nt * 32 + wnn * 16 + jl;
    bpanel[q * BSD + k] = (short)f2bf(Whh_d[(size_t)(gate * Hn + j) * Hn + k]);
  }
  #pragma unroll
  for (int ni = 0; ni < 4; ++ni){
    biasr[ni] = b_d[ni * Hn + jcol];
    wihr[ni]  = Wih_d[ni * Hn + jcol];   // (4H x 1) input weight column
  }
  const float woutr = Wout[jcol];
  const float bov   = bout[0];
  #pragma unroll
  for (int mi = 0; mi < 2; ++mi){
    #pragma unroll
    for (int r = 0; r < 4; ++r){
      int b = brow0 + mi * 16 + r;
      const float* zp  = zbuf + (size_t)b * Ln;
      const float* whr = Wzh + jcol * Ln;
      const float* wcr = Wzc + jcol * Ln;
      float sh = bzh[jcol], sc = bzc[jcol];
      for (int e = 0; e < Ln; ++e){
        float zv = zp[e];
        sh = __builtin_fmaf(zv, whr[e], sh);
        sc = __builtin_fmaf(zv, wcr[e], sc);
      }
      c[mi][r] = tanh_(sc);
      hbuf0[(size_t)b * Hn + jcol] = f2bf(tanh_(sh));
    }
  }
  if (nt == 0){
    for (int i = tid; i < 3 * 64; i += NTHR)     // init all 3 rotating out buffers to b_out
      obuf[(i >> 6) * Bt + mt * 64 + (i & 63)] = bov;
  }
  bars += 32; group_sync(cnt, bars);

  // ---------------- decoder: 1024 autoregressive steps ----------------
  for (int t = 0; t < Tt; ++t){
    const unsigned short* hs = (t & 1) ? hbuf1 : hbuf0;
    unsigned short*       hd = (t & 1) ? hbuf0 : hbuf1;
    float*       oacc  = obuf + (t % 3) * Bt;        // accumulate out_t
    const float* oread = obuf + ((t + 2) % 3) * Bt;  // complete out_{t-1}
    float*       orst  = obuf + ((t + 1) % 3) * Bt;  // reset for step t+1

    float xv[2][4];
    #pragma unroll
    for (int mi = 0; mi < 2; ++mi)
      #pragma unroll
      for (int r = 0; r < 4; ++r)
        xv[mi][r] = (t == 0) ? 0.f : oread[brow0 + mi * 16 + r];

    if (nt == 0){
      if (t > 0)
        for (int i = tid; i < 64; i += NTHR)
          out[(size_t)(mt * 64 + i) * Tt + (t - 1)] = oread[mt * 64 + i];
      for (int i = tid; i < 64; i += NTHR)
        orst[mt * 64 + i] = bov;
    }

    f32x4 acc[2][4];
    #pragma unroll
    for (int mi = 0; mi < 2; ++mi)
      #pragma unroll
      for (int ni = 0; ni < 4; ++ni) acc[mi][ni] = fz;

    const short* bbase = bpanel + (wn * 64 + l15) * BSD + kq;
    const unsigned short* ap = hs + (size_t)arow0 * Hn + kq;
    #pragma unroll 4
    for (int k0 = 0; k0 < KD; k0 += 32){
      short8 a[2];
      #pragma unroll
      for (int mi = 0; mi < 2; ++mi)
        a[mi] = *(const short8*)(ap + mi * 16 * Hn + k0);
      #pragma unroll
      for (int ni = 0; ni < 4; ++ni){
        short8 bv = *(const short8*)(bbase + ni * 16 * BSD + k0);
        #pragma unroll
        for (int mi = 0; mi < 2; ++mi)
          acc[mi][ni] = __builtin_amdgcn_mfma_f32_16x16x32_bf16(a[mi], bv, acc[mi][ni], 0, 0, 0);
      }
    }
    #pragma unroll
    for (int mi = 0; mi < 2; ++mi){
      #pragma unroll
      for (int r = 0; r < 4; ++r){
        float x = xv[mi][r];
        float gi = acc[mi][0][r] + biasr[0] + x * wihr[0];
        float gf = acc[mi][1][r] + biasr[1] + x * wihr[1];
        float gg = acc[mi][2][r] + biasr[2] + x * wihr[2];
        float go = acc[mi][3][r] + biasr[3] + x * wihr[3];
        float cn = sigm(gf) * c[mi][r] + sigm(gi) * tanh_(gg);
        c[mi][r] = cn;
        float hn = sigm(go) * tanh_(cn);
        int b = brow0 + mi * 16 + r;
        hd[(size_t)b * Hn + jcol] = f2bf(hn);
        float pv = hn * woutr;                 // partial of out_t[b] over 16 j's
        pv += __shfl_xor(pv, 1);
        pv += __shfl_xor(pv, 2);
        pv += __shfl_xor(pv, 4);
        pv += __shfl_xor(pv, 8);
        if (l15 == 0) atomicAdd(&oacc[b], pv);
      }
    }
    bars += 32; group_sync(cnt, bars);
  }
  // drain last output column (t = 1023 accumulated into buf (1023%3)==0)
  if (nt == 0)
    for (int i = tid; i < 64; i += NTHR)
      out[(size_t)(mt * 64 + i) * Tt + (Tt - 1)] = obuf[0 * Bt + mt * 64 + i];
}

extern "C" void kernel_launch(void* const* d_in, const int* in_sizes, int n_in,
                              void* d_out, int out_size, void* d_ws, size_t ws_size,
                              hipStream_t stream){
  (void)in_sizes; (void)n_in; (void)out_size; (void)ws_size;
  const float* src   = (const float*)d_in[0];
  const float* eps   = (const float*)d_in[1];
  // d_in[2] = tgt_len (int, fixed 1024)
  const float* Wih_e = (const float*)d_in[3];
  const float* Whh_e = (const float*)d_in[4];
  const float* b_e   = (const float*)d_in[5];
  const float* Wmu   = (const float*)d_in[6];
  const float* bmu   = (const float*)d_in[7];
  const float* Wlv   = (const float*)d_in[8];
  const float* blv   = (const float*)d_in[9];
  const float* Wzh   = (const float*)d_in[10];
  const float* bzh   = (const float*)d_in[11];
  const float* Wzc   = (const float*)d_in[12];
  const float* bzc   = (const float*)d_in[13];
  const float* Wih_d = (const float*)d_in[14];
  const float* Whh_d = (const float*)d_in[15];
  const float* b_d   = (const float*)d_in[16];
  const float* Wout  = (const float*)d_in[17];
  const float* bout  = (const float*)d_in[18];

  char* ws = (char*)d_ws;
  unsigned*       cnt  = (unsigned*)ws;                            // 1024 B (8 counters, 128B apart)
  unsigned short* h0   = (unsigned short*)(ws + 1024);             // 1 MB
  unsigned short* h1   = (unsigned short*)(ws + 1024 + 1048576);   // 1 MB
  float*          zbuf = (float*)(ws + 1024 + 2 * 1048576);        // 256 KB
  float*          obuf = (float*)(ws + 1024 + 2 * 1048576 + 262144); // 12 KB

  hipFuncSetAttribute((const void*)vae_fused,
                      hipFuncAttributeMaxDynamicSharedMemorySize, LDS_BYTES);
  hipMemsetAsync(cnt, 0, 1024, stream);
  hipLaunchKernelGGL(vae_fused, dim3(NWG), dim3(NTHR), LDS_BYTES, stream,
                     src, eps, Wih_e, Whh_e, b_e, Wmu, bmu, Wlv, blv,
                     Wzh, bzh, Wzc, bzc, Wih_d, Whh_d, b_d, Wout, bout,
                     (float*)d_out, cnt, h0, h1, zbuf, obuf);
}

// Round 2
// 16652.596 us; speedup vs baseline: 3.7636x; 3.7636x over previous
//
#include <hip/hip_runtime.h>

// Seq2Seq VAE fused persistent kernel for MI355X (gfx950).
// 16 groups of 16 WGs keyed by M-tile; fence-free cross-WG exchange via
// sc0sc1 (coherence-point) stores/loads; relaxed-atomic spin barrier.
// Weights persistent in LDS (146KB/CU); bf16 MFMA 16x16x32; h exchange bf16.

#define NWG  256
#define NTHR 256

typedef __attribute__((ext_vector_type(8))) short short8;
typedef __attribute__((ext_vector_type(4))) float f32x4;
typedef __attribute__((ext_vector_type(4))) unsigned int u32x4;

constexpr int Bt = 1024;   // batch
constexpr int Tt = 1024;   // seq len
constexpr int In = 64;     // input size
constexpr int Hn = 512;    // hidden
constexpr int Ln = 64;     // latent
constexpr int KE = In + Hn;      // 576
constexpr int BSE = KE + 8;      // 584 (stride ≡ 4 dwords mod 32 -> 2-way, free)
constexpr int KD = Hn;           // 512
constexpr int BSD = KD + 8;      // 520
constexpr int LDS_BYTES = 128 * BSE * 2;   // 149504
constexpr int AP_MI = 16 * Hn;   // A row-block stride in shorts

__device__ __forceinline__ float bf2f(unsigned short s){
  unsigned u = ((unsigned)s) << 16; float f; __builtin_memcpy(&f, &u, 4); return f;
}
__device__ __forceinline__ unsigned short f2bf(float f){
  unsigned u; __builtin_memcpy(&u, &f, 4);
  u += 0x7FFFu + ((u >> 16) & 1u);
  return (unsigned short)(u >> 16);
}
__device__ __forceinline__ float sigm(float x){ return 1.0f / (1.0f + __expf(-x)); }
__device__ __forceinline__ float tanh_(float x){ float e = __expf(2.0f * x); return 1.0f - 2.0f / (e + 1.0f); }

// ---- coherence-point (MALL) access helpers: bypass L1+L2 with sc0 sc1 ----
__device__ __forceinline__ u32x4 ldcc(const void* p){
  u32x4 r;
  asm volatile("global_load_dwordx4 %0, %1, off sc0 sc1" : "=&v"(r) : "v"(p) : "memory");
  return r;
}
__device__ __forceinline__ float ld32cc(const void* p){
  float r;
  asm volatile("global_load_dword %0, %1, off sc0 sc1" : "=&v"(r) : "v"(p) : "memory");
  return r;
}
__device__ __forceinline__ void st16cc(void* p, unsigned v){
  asm volatile("global_store_short %0, %1, off sc0 sc1" :: "v"(p), "v"(v) : "memory");
}
__device__ __forceinline__ void st32cc(void* p, float v){
  asm volatile("global_store_dword %0, %1, off sc0 sc1" :: "v"(p), "v"(v) : "memory");
}
__device__ __forceinline__ void st128cc(void* p, u32x4 v){
  asm volatile("global_store_dwordx4 %0, %1, off sc0 sc1" :: "v"(p), "v"(v) : "memory");
}

// Fence-free group barrier: drain this wave's (sc0sc1) stores, arrive, spin.
__device__ __forceinline__ void group_sync(unsigned* cnt, unsigned target){
  asm volatile("s_waitcnt vmcnt(0)" ::: "memory");
  __syncthreads();
  if (threadIdx.x == 0){
    __hip_atomic_fetch_add(cnt, 1u, __ATOMIC_RELAXED, __HIP_MEMORY_SCOPE_AGENT);
    while (__hip_atomic_load(cnt, __ATOMIC_RELAXED, __HIP_MEMORY_SCOPE_AGENT) < target)
      __builtin_amdgcn_s_sleep(2);
  }
  __syncthreads();
}

#define SB0 __builtin_amdgcn_sched_barrier(0)

// issue one chunk (4 K-iters x 2 row-blocks) of A loads into parity P
#define LOADC(P, CBASE) do{                                              \
    _Pragma("unroll") for (int ti_ = 0; ti_ < 4; ++ti_){                 \
      A[P][ti_][0] = ldcc(ap + (CBASE) + ti_ * 32);                      \
      A[P][ti_][1] = ldcc(ap + AP_MI + (CBASE) + ti_ * 32);              \
    } }while(0)

// wait until chunk parity P complete (N = allowed outstanding), tie regs
#define WAITC(P, N) do{                                                  \
    asm volatile("s_waitcnt vmcnt(" N ")"                                \
      : "+v"(A[P][0][0]), "+v"(A[P][0][1]), "+v"(A[P][1][0]),            \
        "+v"(A[P][1][1]), "+v"(A[P][2][0]), "+v"(A[P][2][1]),            \
        "+v"(A[P][3][0]), "+v"(A[P][3][1]) :: "memory");                 \
    SB0; }while(0)

// consume chunk parity P: 4 K-iters of B ds_reads + MFMAs. K0: B-side k base.
#define COMPC(P, K0, BB, BS) do{                                         \
    _Pragma("unroll") for (int ti_ = 0; ti_ < 4; ++ti_){                 \
      short8 a0_ = __builtin_bit_cast(short8, A[P][ti_][0]);             \
      short8 a1_ = __builtin_bit_cast(short8, A[P][ti_][1]);             \
      _Pragma("unroll") for (int ni_ = 0; ni_ < 4; ++ni_){               \
        short8 bv_ = *(const short8*)((BB) + ni_ * 16 * (BS) + (K0) + ti_ * 32); \
        acc[0][ni_] = __builtin_amdgcn_mfma_f32_16x16x32_bf16(a0_, bv_, acc[0][ni_], 0, 0, 0); \
        acc[1][ni_] = __builtin_amdgcn_mfma_f32_16x16x32_bf16(a1_, bv_, acc[1][ni_], 0, 0, 0); \
      } } }while(0)

extern "C" __global__ void __launch_bounds__(NTHR, 1)
vae_fused(const float* __restrict__ src, const float* __restrict__ eps,
          const float* __restrict__ Wih_e, const float* __restrict__ Whh_e, const float* __restrict__ b_e,
          const float* __restrict__ Wmu, const float* __restrict__ bmu,
          const float* __restrict__ Wlv, const float* __restrict__ blv,
          const float* __restrict__ Wzh, const float* __restrict__ bzh,
          const float* __restrict__ Wzc, const float* __restrict__ bzc,
          const float* __restrict__ Wih_d, const float* __restrict__ Whh_d, const float* __restrict__ b_d,
          const float* __restrict__ Wout, const float* __restrict__ bout,
          float* __restrict__ out,
          unsigned* cnt_all, unsigned short* hbuf0, unsigned short* hbuf1,
          float* zbuf, float* obuf)
{
  const int tid  = threadIdx.x;
  const int wg   = blockIdx.x;
  const int lane = tid & 63;
  const int wave = tid >> 6;
  const int wm   = wave >> 1, wn = wave & 1;  // 2x2 wave tiling of 64x128
  const int mt   = wg & 15;                   // M tile (64 rows) == group id
  const int nt   = wg >> 4;                   // N tile (128 gate-cols), 0..15
  unsigned* cnt  = cnt_all + mt * 32;         // 128B-spaced counters
  unsigned bars  = 0;

  extern __shared__ short bpanel[];           // [128][BSE or BSD]

  const int l15   = lane & 15;
  const int l4    = lane >> 4;
  const int kq    = l4 * 8;
  const int jcol  = nt * 32 + wn * 16 + l15;
  const int arow0 = mt * 64 + wm * 32 + l15;
  const int brow0 = mt * 64 + wm * 32 + l4 * 4;

  // ---------------- prep: zero h0 (group rows, at MALL), encoder B panel ----
  {
    const int idx = nt * NTHR + tid;          // 0..4095 == 64 rows * 64 col8s
    const u32x4 z = {0u, 0u, 0u, 0u};
    st128cc(hbuf0 + (size_t)(mt * 64 + (idx >> 6)) * Hn + (idx & 63) * 8, z);
  }
  for (int idx = tid; idx < 128 * KE; idx += NTHR){
    int q = idx / KE;
    int k = idx - q * KE;
    int gate = (q >> 4) & 3, jl = q & 15, wnn = (q >> 6) & 1;
    int j = nt * 32 + wnn * 16 + jl;
    int r = gate * Hn + j;
    float v = (k < In) ? Wih_e[r * In + k] : Whh_e[(size_t)r * Hn + (k - In)];
    bpanel[q * BSE + k] = (short)f2bf(v);
  }
  float biasr[4], wihr[4];
  #pragma unroll
  for (int ni = 0; ni < 4; ++ni) biasr[ni] = b_e[ni * Hn + jcol];
  bars += 16; group_sync(cnt, bars);

  float c[2][4] = {{0.f,0.f,0.f,0.f},{0.f,0.f,0.f,0.f}};
  const f32x4 fz = {0.f, 0.f, 0.f, 0.f};
  u32x4 A[2][4][2];                           // chunk double-buffer (static idx only)

  // ---------------- encoder: 1024 steps ----------------
  for (int t = 0; t < Tt; ++t){
    const unsigned short* hs = (t & 1) ? hbuf1 : hbuf0;
    unsigned short*       hd = (t & 1) ? hbuf0 : hbuf1;
    f32x4 acc[2][4];
    #pragma unroll
    for (int mi = 0; mi < 2; ++mi)
      #pragma unroll
      for (int ni = 0; ni < 4; ++ni) acc[mi][ni] = fz;

    const short* bbase = bpanel + (wn * 64 + l15) * BSE + kq;

    // src part (K=0..64): plain cached loads, convert in-register
    short8 sa[2][2];
    #pragma unroll
    for (int mi = 0; mi < 2; ++mi){
      const float* sp = src + ((size_t)(arow0 + mi * 16) * Tt + t) * In + kq;
      f32x4 f0 = *(const f32x4*)sp;
      f32x4 f1 = *(const f32x4*)(sp + 4);
      f32x4 f2 = *(const f32x4*)(sp + 32);
      f32x4 f3 = *(const f32x4*)(sp + 36);
      short8 a0, a1;
      #pragma unroll
      for (int e = 0; e < 4; ++e){
        a0[e] = (short)f2bf(f0[e]); a0[4 + e] = (short)f2bf(f1[e]);
        a1[e] = (short)f2bf(f2[e]); a1[4 + e] = (short)f2bf(f3[e]);
      }
      sa[mi][0] = a0; sa[mi][1] = a1;
    }

    const unsigned short* ap = hs + (size_t)arow0 * Hn + kq;
    LOADC(0, 0); LOADC(1, 128);

    // src MFMAs cover chunk-0 MALL latency
    #pragma unroll
    for (int kk = 0; kk < 2; ++kk)
      #pragma unroll
      for (int ni = 0; ni < 4; ++ni){
        short8 bv = *(const short8*)(bbase + ni * 16 * BSE + kk * 32);
        acc[0][ni] = __builtin_amdgcn_mfma_f32_16x16x32_bf16(sa[0][kk], bv, acc[0][ni], 0, 0, 0);
        acc[1][ni] = __builtin_amdgcn_mfma_f32_16x16x32_bf16(sa[1][kk], bv, acc[1][ni], 0, 0, 0);
      }

    WAITC(0, "8"); COMPC(0, In + 0,   bbase, BSE);
    LOADC(0, 256);
    WAITC(1, "8"); COMPC(1, In + 128, bbase, BSE);
    LOADC(1, 384);
    WAITC(0, "8"); COMPC(0, In + 256, bbase, BSE);
    WAITC(1, "0"); COMPC(1, In + 384, bbase, BSE);

    #pragma unroll
    for (int mi = 0; mi < 2; ++mi){
      #pragma unroll
      for (int r = 0; r < 4; ++r){
        float gi = acc[mi][0][r] + biasr[0];
        float gf = acc[mi][1][r] + biasr[1];
        float gg = acc[mi][2][r] + biasr[2];
        float go = acc[mi][3][r] + biasr[3];
        float cn = sigm(gf) * c[mi][r] + sigm(gi) * tanh_(gg);
        c[mi][r] = cn;
        float hn = sigm(go) * tanh_(cn);
        st16cc(hd + (size_t)(brow0 + mi * 16 + r) * Hn + jcol, (unsigned)f2bf(hn));
      }
    }
    bars += 16; group_sync(cnt, bars);
  }
  // h_n in hbuf0

  // ---------------- mu / logvar / z ----------------
  {
    const int lt = nt * NTHR + tid;     // 4096 == 64 rows * 64 latents
    const int b  = mt * 64 + (lt >> 6);
    const int l  = lt & 63;
    const unsigned short* hp = hbuf0 + (size_t)b * Hn;
    const float* wmrow = Wmu + l * Hn;
    const float* wlrow = Wlv + l * Hn;
    float smu = 0.f, slv = 0.f;
    for (int jj = 0; jj < Hn; jj += 32){
      u32x4 v0 = ldcc(hp + jj), v1 = ldcc(hp + jj + 8), v2 = ldcc(hp + jj + 16), v3 = ldcc(hp + jj + 24);
      asm volatile("s_waitcnt vmcnt(0)" : "+v"(v0), "+v"(v1), "+v"(v2), "+v"(v3) :: "memory");
      short8 h0 = __builtin_bit_cast(short8, v0);
      short8 h1 = __builtin_bit_cast(short8, v1);
      short8 h2 = __builtin_bit_cast(short8, v2);
      short8 h3 = __builtin_bit_cast(short8, v3);
      #pragma unroll
      for (int e = 0; e < 8; ++e){
        float f0 = bf2f((unsigned short)h0[e]), f1 = bf2f((unsigned short)h1[e]);
        float f2 = bf2f((unsigned short)h2[e]), f3 = bf2f((unsigned short)h3[e]);
        smu = __builtin_fmaf(f0, wmrow[jj + e], smu);      slv = __builtin_fmaf(f0, wlrow[jj + e], slv);
        smu = __builtin_fmaf(f1, wmrow[jj + 8 + e], smu);  slv = __builtin_fmaf(f1, wlrow[jj + 8 + e], slv);
        smu = __builtin_fmaf(f2, wmrow[jj + 16 + e], smu); slv = __builtin_fmaf(f2, wlrow[jj + 16 + e], slv);
        smu = __builtin_fmaf(f3, wmrow[jj + 24 + e], smu); slv = __builtin_fmaf(f3, wlrow[jj + 24 + e], slv);
      }
    }
    smu += bmu[l]; slv += blv[l];
    out[(size_t)Bt * Tt + (size_t)b * Ln + l] = smu;
    out[(size_t)Bt * Tt + (size_t)Bt * Ln + (size_t)b * Ln + l] = slv;
    st32cc(zbuf + (size_t)b * Ln + l, smu + eps[(size_t)b * Ln + l] * __expf(0.5f * slv));
  }
  bars += 16; group_sync(cnt, bars);

  // ---------------- decoder init ----------------
  for (int idx = tid; idx < 128 * KD; idx += NTHR){
    int q = idx >> 9, k = idx & 511;
    int gate = (q >> 4) & 3, jl = q & 15, wnn = (q >> 6) & 1;
    int j = nt * 32 + wnn * 16 + jl;
    bpanel[q * BSD + k] = (short)f2bf(Whh_d[(size_t)(gate * Hn + j) * Hn + k]);
  }
  #pragma unroll
  for (int ni = 0; ni < 4; ++ni){
    biasr[ni] = b_d[ni * Hn + jcol];
    wihr[ni]  = Wih_d[ni * Hn + jcol];
  }
  const float woutr = Wout[jcol];
  const float bov   = bout[0];
  #pragma unroll
  for (int mi = 0; mi < 2; ++mi){
    #pragma unroll
    for (int r = 0; r < 4; ++r){
      int b = brow0 + mi * 16 + r;
      const float* zp  = zbuf + (size_t)b * Ln;
      const float* whr = Wzh + jcol * Ln;
      const float* wcr = Wzc + jcol * Ln;
      float sh = bzh[jcol], sc = bzc[jcol];
      for (int e0 = 0; e0 < Ln; e0 += 16){
        u32x4 z0 = ldcc(zp + e0), z1 = ldcc(zp + e0 + 4), z2 = ldcc(zp + e0 + 8), z3 = ldcc(zp + e0 + 12);
        asm volatile("s_waitcnt vmcnt(0)" : "+v"(z0), "+v"(z1), "+v"(z2), "+v"(z3) :: "memory");
        f32x4 zf0 = __builtin_bit_cast(f32x4, z0);
        f32x4 zf1 = __builtin_bit_cast(f32x4, z1);
        f32x4 zf2 = __builtin_bit_cast(f32x4, z2);
        f32x4 zf3 = __builtin_bit_cast(f32x4, z3);
        #pragma unroll
        for (int e = 0; e < 4; ++e){
          sh = __builtin_fmaf(zf0[e], whr[e0 + e], sh);      sc = __builtin_fmaf(zf0[e], wcr[e0 + e], sc);
          sh = __builtin_fmaf(zf1[e], whr[e0 + 4 + e], sh);  sc = __builtin_fmaf(zf1[e], wcr[e0 + 4 + e], sc);
          sh = __builtin_fmaf(zf2[e], whr[e0 + 8 + e], sh);  sc = __builtin_fmaf(zf2[e], wcr[e0 + 8 + e], sc);
          sh = __builtin_fmaf(zf3[e], whr[e0 + 12 + e], sh); sc = __builtin_fmaf(zf3[e], wcr[e0 + 12 + e], sc);
        }
      }
      c[mi][r] = tanh_(sc);
      st16cc(hbuf0 + (size_t)b * Hn + jcol, (unsigned)f2bf(tanh_(sh)));
    }
  }
  if (nt == 0 && tid < 3 * 64)
    st32cc(obuf + (tid >> 6) * Bt + mt * 64 + (tid & 63), bov);
  bars += 16; group_sync(cnt, bars);

  // ---------------- decoder: 1024 autoregressive steps ----------------
  for (int t = 0; t < Tt; ++t){
    const unsigned short* hs = (t & 1) ? hbuf1 : hbuf0;
    unsigned short*       hd = (t & 1) ? hbuf0 : hbuf1;
    float*       oacc  = obuf + (t % 3) * Bt;
    const float* oread = obuf + ((t + 2) % 3) * Bt;
    float*       orst  = obuf + ((t + 1) % 3) * Bt;

    if (nt == 0){
      if (t > 0 && tid < 64){
        float v = ld32cc(oread + mt * 64 + tid);
        asm volatile("s_waitcnt vmcnt(0)" : "+v"(v) :: "memory");
        out[(size_t)(mt * 64 + tid) * Tt + (t - 1)] = v;
      }
      if (tid < 64) st32cc(orst + mt * 64 + tid, bov);
    }

    float xv[2][4];
    #pragma unroll
    for (int mi = 0; mi < 2; ++mi)
      #pragma unroll
      for (int r = 0; r < 4; ++r)
        xv[mi][r] = ld32cc(oread + brow0 + mi * 16 + r);

    f32x4 acc[2][4];
    #pragma unroll
    for (int mi = 0; mi < 2; ++mi)
      #pragma unroll
      for (int ni = 0; ni < 4; ++ni) acc[mi][ni] = fz;

    const short* bbase = bpanel + (wn * 64 + l15) * BSD + kq;
    const unsigned short* ap = hs + (size_t)arow0 * Hn + kq;

    LOADC(0, 0); LOADC(1, 128);
    WAITC(0, "8"); COMPC(0, 0,   bbase, BSD);
    LOADC(0, 256);
    WAITC(1, "8"); COMPC(1, 128, bbase, BSD);
    LOADC(1, 384);
    WAITC(0, "8"); COMPC(0, 256, bbase, BSD);
    WAITC(1, "0"); COMPC(1, 384, bbase, BSD);

    asm volatile("s_waitcnt vmcnt(0)"
      : "+v"(xv[0][0]), "+v"(xv[0][1]), "+v"(xv[0][2]), "+v"(xv[0][3]),
        "+v"(xv[1][0]), "+v"(xv[1][1]), "+v"(xv[1][2]), "+v"(xv[1][3]) :: "memory");

    #pragma unroll
    for (int mi = 0; mi < 2; ++mi){
      #pragma unroll
      for (int r = 0; r < 4; ++r){
        float x = (t == 0) ? 0.f : xv[mi][r];
        float gi = acc[mi][0][r] + biasr[0] + x * wihr[0];
        float gf = acc[mi][1][r] + biasr[1] + x * wihr[1];
        float gg = acc[mi][2][r] + biasr[2] + x * wihr[2];
        float go = acc[mi][3][r] + biasr[3] + x * wihr[3];
        float cn = sigm(gf) * c[mi][r] + sigm(gi) * tanh_(gg);
        c[mi][r] = cn;
        float hn = sigm(go) * tanh_(cn);
        int b = brow0 + mi * 16 + r;
        st16cc(hd + (size_t)b * Hn + jcol, (unsigned)f2bf(hn));
        float pv = hn * woutr;
        pv += __shfl_xor(pv, 1);
        pv += __shfl_xor(pv, 2);
        pv += __shfl_xor(pv, 4);
        pv += __shfl_xor(pv, 8);
        if (l15 == 0)
          __hip_atomic_fetch_add(&oacc[b], pv, __ATOMIC_RELAXED, __HIP_MEMORY_SCOPE_AGENT);
      }
    }
    bars += 16; group_sync(cnt, bars);
  }
  // drain last output column (t=1023 accumulated into buf 0)
  if (nt == 0 && tid < 64){
    float v = ld32cc(obuf + 0 * Bt + mt * 64 + tid);
    asm volatile("s_waitcnt vmcnt(0)" : "+v"(v) :: "memory");
    out[(size_t)(mt * 64 + tid) * Tt + (Tt - 1)] = v;
  }
}

extern "C" void kernel_launch(void* const* d_in, const int* in_sizes, int n_in,
                              void* d_out, int out_size, void* d_ws, size_t ws_size,
                              hipStream_t stream){
  (void)in_sizes; (void)n_in; (void)out_size; (void)ws_size;
  const float* src   = (const float*)d_in[0];
  const float* eps   = (const float*)d_in[1];
  const float* Wih_e = (const float*)d_in[3];
  const float* Whh_e = (const float*)d_in[4];
  const float* b_e   = (const float*)d_in[5];
  const float* Wmu   = (const float*)d_in[6];
  const float* bmu   = (const float*)d_in[7];
  const float* Wlv   = (const float*)d_in[8];
  const float* blv   = (const float*)d_in[9];
  const float* Wzh   = (const float*)d_in[10];
  const float* bzh   = (const float*)d_in[11];
  const float* Wzc   = (const float*)d_in[12];
  const float* bzc   = (const float*)d_in[13];
  const float* Wih_d = (const float*)d_in[14];
  const float* Whh_d = (const float*)d_in[15];
  const float* b_d   = (const float*)d_in[16];
  const float* Wout  = (const float*)d_in[17];
  const float* bout  = (const float*)d_in[18];

  char* ws = (char*)d_ws;
  unsigned*       cnt  = (unsigned*)ws;                              // 16 counters, 128B apart
  unsigned short* h0   = (unsigned short*)(ws + 4096);               // 1 MB
  unsigned short* h1   = (unsigned short*)(ws + 4096 + 1048576);     // 1 MB
  float*          zbuf = (float*)(ws + 4096 + 2 * 1048576);          // 256 KB
  float*          obuf = (float*)(ws + 4096 + 2 * 1048576 + 262144); // 12 KB

  hipFuncSetAttribute((const void*)vae_fused,
                      hipFuncAttributeMaxDynamicSharedMemorySize, LDS_BYTES);
  hipMemsetAsync(cnt, 0, 2048, stream);
  hipLaunchKernelGGL(vae_fused, dim3(NWG), dim3(NTHR), LDS_BYTES, stream,
                     src, eps, Wih_e, Whh_e, b_e, Wmu, bmu, Wlv, blv,
                     Wzh, bzh, Wzc, bzc, Wih_d, Whh_d, b_d, Wout, bout,
                     (float*)d_out, cnt, h0, h1, zbuf, obuf);
}